// Round 1
// baseline (5646.767 us; speedup 1.0000x reference)
//
#include <hip/hip_runtime.h>

typedef __attribute__((ext_vector_type(8))) short bf16x8_t;
typedef __attribute__((ext_vector_type(4))) float f32x4_t;
typedef __attribute__((ext_vector_type(4))) int i32x4_t;

#define NPART 332   // 21248/64 column-strip partials for the classifier LSE

__device__ __forceinline__ unsigned short f2b(float f) {
  unsigned int u = __builtin_bit_cast(unsigned int, f);
  u += 0x7fffu + ((u >> 16) & 1u);
  return (unsigned short)(u >> 16);
}
__device__ __forceinline__ float b2f(unsigned short h) {
  unsigned int u = ((unsigned int)h) << 16;
  return __builtin_bit_cast(float, u);
}

// async global->LDS, 16B per lane; LDS dest is wave-uniform base + lane*16
__device__ __forceinline__ void async16(const unsigned short* g, unsigned short* l) {
  __builtin_amdgcn_global_load_lds(
      (const __attribute__((address_space(1))) unsigned int*)g,
      (__attribute__((address_space(3))) unsigned int*)l, 16, 0, 0);
}

// ---------------- transpose+convert: in f32 [K][N] -> out bf16 [Npad][K] ----------------
__global__ void transpose_w(const float* __restrict__ in, unsigned short* __restrict__ out,
                            int K, int N, int Npad, long inBatch, long outBatch)
{
  __shared__ float tile[32][33];
  const int bz = blockIdx.z;
  in += (long)bz * inBatch;
  out += (long)bz * outBatch;
  const int k0 = blockIdx.x * 32, n0 = blockIdx.y * 32;
  const int tx = threadIdx.x, ty = threadIdx.y;  // 32 x 8
#pragma unroll
  for (int i = 0; i < 32; i += 8) {
    const int k = k0 + ty + i, n = n0 + tx;
    tile[ty + i][tx] = (k < K && n < N) ? in[(long)k * N + n] : 0.f;
  }
  __syncthreads();
#pragma unroll
  for (int i = 0; i < 32; i += 8) {
    const int n = n0 + ty + i, k = k0 + tx;
    if (n < Npad && k < K) out[(long)n * K + k] = f2b(tile[tx][ty + i]);
  }
}

__global__ void build_bqkv(const float* __restrict__ bq, const float* __restrict__ bk,
                           const float* __restrict__ bv, float* __restrict__ out)
{
  const int i = blockIdx.x * 256 + threadIdx.x;
  if (i >= 12 * 2304) return;
  const int l = i / 2304, j = i % 2304;
  float v;
  if (j < 768) v = bq[l * 768 + j];
  else if (j < 1536) v = bk[l * 768 + j - 768];
  else v = bv[l * 768 + j - 1536];
  out[i] = v;
}
__global__ void build_clsb(const float* __restrict__ cb, float* __restrict__ out)
{
  const int i = blockIdx.x * 256 + threadIdx.x;
  if (i < 21248) out[i] = (i < 21128) ? cb[i] : 0.f;
}

// ---------------- GEMM: C[M][N] = A[M][K] (bf16) x Bt[N][K] (bf16) ----------------
// Classic 2-stage dbuf kernel: kept for the N=768 sites (Wo, FFN2) where a
// 256-wide tile grid would underfill the chip.
template <int TM, int TN>
__global__ __launch_bounds__(256)
void gemm_db(const unsigned short* __restrict__ A,
             const unsigned short* __restrict__ Bt,
             const float* __restrict__ bias,
             const float* __restrict__ resid,
             float* __restrict__ Cf,
             unsigned short* __restrict__ Cb,
             int K, int ldc, int flags,
             const int* __restrict__ yv, float2* __restrict__ st2,
             float* __restrict__ tgt)
{
  constexpr int MT = TM / 32, NT = TN / 32;
  constexpr int STRIDE = (TM + TN) * 64;
  __shared__ unsigned short sh[2 * STRIDE];
  const int tid = threadIdx.x;
  const int wave = tid >> 6, lane = tid & 63;
  const int quad = lane >> 4, lidx = lane & 15;
  const int m0 = blockIdx.x * TM, n0 = blockIdx.y * TN;
  const int wm = (wave >> 1) * (TM / 2), wn = (wave & 1) * (TN / 2);
  f32x4_t acc[MT][NT] = {};
  const int r8 = lane >> 3;                 // row within 8-row group
  const int csw = ((lane & 7) ^ r8) * 8;    // swizzled source chunk (elements)
  const unsigned short* ag = A + (long)(m0 + wave * (TM / 4) + r8) * K + csw;
  const unsigned short* bg = Bt + (long)(n0 + wave * (TN / 4) + r8) * K + csw;
  const int laOff = wave * (TM / 4) * 64;
  const int lbOff = TM * 64 + wave * (TN / 4) * 64;

  auto issue = [&](int k0, int st) {
    unsigned short* la0 = sh + st * STRIDE + laOff;
    unsigned short* lb0 = sh + st * STRIDE + lbOff;
#pragma unroll
    for (int i = 0; i < TM / 32; i++) async16(ag + (long)(i * 8) * K + k0, la0 + i * 512);
#pragma unroll
    for (int i = 0; i < TN / 32; i++) async16(bg + (long)(i * 8) * K + k0, lb0 + i * 512);
  };
  auto compute = [&](int st) {
    const unsigned short* lA = sh + st * STRIDE;
    const unsigned short* lB = lA + TM * 64;
#pragma unroll
    for (int kk = 0; kk < 2; kk++) {
      bf16x8_t af[MT], bf[NT];
#pragma unroll
      for (int t = 0; t < MT; t++)
        af[t] = *(const bf16x8_t*)&lA[(wm + t * 16 + lidx) * 64 + ((kk * 4 + quad) ^ (lidx & 7)) * 8];
#pragma unroll
      for (int t = 0; t < NT; t++)
        bf[t] = *(const bf16x8_t*)&lB[(wn + t * 16 + lidx) * 64 + ((kk * 4 + quad) ^ (lidx & 7)) * 8];
#pragma unroll
      for (int mt = 0; mt < MT; mt++)
#pragma unroll
        for (int nt = 0; nt < NT; nt++)
          acc[mt][nt] = __builtin_amdgcn_mfma_f32_16x16x32_bf16(af[mt], bf[nt], acc[mt][nt], 0, 0, 0);
    }
  };

  issue(0, 0);
  for (int k0 = 0; k0 < K; k0 += 128) {    // K % 128 == 0 for all shapes here
    __syncthreads();
    if (k0 + 64 < K) issue(k0 + 64, 1);
    compute(0);
    __syncthreads();
    if (k0 + 128 < K) issue(k0 + 128, 0);
    compute(1);
  }

#pragma unroll
  for (int mt = 0; mt < MT; mt++) {
#pragma unroll
    for (int nt = 0; nt < NT; nt++) {
#pragma unroll
      for (int r = 0; r < 4; r++) {
        const int row = m0 + wm + mt * 16 + quad * 4 + r;
        const int col = n0 + wn + nt * 16 + lidx;
        float v = acc[mt][nt][r];
        if (bias) v += bias[col];
        if (flags & 1) v = 0.5f * v * (1.0f + erff(v * 0.70710678118f));
        const long o = (long)row * ldc + col;
        if (resid) v += resid[o];
        if (Cf) Cf[o] = v;
        if (Cb) Cb[o] = f2b(v);
      }
    }
  }
}

// ---------------- 256x256 8-phase pipelined GEMM (T2+T3+T4+T5) ----------------
// C[M][N] = A[M][K] (bf16) x Bt[N][K] (bf16). Requires K % 32 == 0, K >= 96,
// M % 256 == 0, N % 256 == 0. 512 thr = 8 waves (2M x 4N); per-wave C = 128x64.
//
// LDS: 4 rotating chunk-slots (128 KiB dynamic). chunk c = K-slice [32c,32c+32):
//   slot = c & 3, slot = { A[256][32] (16KB) | B[256][32] (16KB) }.
// Paired-row layout inside a region: 128B line L holds rows {2L,2L+1}; the 8
//   16B-chunks of a line are placed at c' = c ^ (L&7) with c = (row&1)*4 + k/8.
//   -> fragment ds_read_b128 (16 rows x 4 k-quads) lands 2 lanes/bank: free.
//   global_load_lds writes LINEARLY; the per-lane GLOBAL source applies the
//   inverse permutation (rowAdd/kAdd below), so write+read swizzles match.
// Schedule per chunk (2 phases):
//   sub0: ds_read B[n0..3]+A[m0..3] | stage B(c+2) | bar | lgkm(0) | 16 MFMA | bar
//   sub1: ds_read A[m4..7]          | stage A(c+3) | bar | lgkm(0) | 16 MFMA |
//         vmcnt(6) (tail: 4 -> 0) | bar            <- counted, never 0 mid-loop
// flags: 1 = gelu, 2 = fused log-sum-exp epilogue (classifier; no C store)
__global__ __launch_bounds__(512, 2)
void gemm8p(const unsigned short* __restrict__ A,
            const unsigned short* __restrict__ Bt,
            const float* __restrict__ bias,
            const float* __restrict__ resid,
            float* __restrict__ Cf,
            unsigned short* __restrict__ Cb,
            int K, int ldc, int flags,
            const int* __restrict__ yv, float2* __restrict__ st2,
            float* __restrict__ tgt)
{
  extern __shared__ unsigned short sh[];       // 4 * 16384 shorts = 128 KiB
  const int tid = threadIdx.x;
  const int wave = tid >> 6, lane = tid & 63;
  const int quad = lane >> 4, lidx = lane & 15;
  const int wr = wave >> 2, wc = wave & 3;     // 2M x 4N wave grid
  const int m0 = blockIdx.x * 256, n0 = blockIdx.y * 256;
  const int NC = K >> 5;                       // 32-wide K chunks
  f32x4_t acc[8][4] = {};

  // ---- staging: lane -> (row, k) inside a 1KB window (8 lines) ----
  const int cst = (lane & 7) ^ (lane >> 3);            // stored chunk id c
  const int rowAdd = 2 * (lane >> 3) + (cst >> 2);     // row within 16-row window
  const int kAdd = (cst & 3) * 8;                      // k within 32-slice
  // wave covers windows {2*wave, 2*wave+1} = rows 32*wave .. 32*wave+31
  const unsigned short* agA  = A  + (long)(m0 + wave * 32 + rowAdd) * K + kAdd;
  const unsigned short* agA2 = A  + (long)(m0 + wave * 32 + 16 + rowAdd) * K + kAdd;
  const unsigned short* bgB  = Bt + (long)(n0 + wave * 32 + rowAdd) * K + kAdd;
  const unsigned short* bgB2 = Bt + (long)(n0 + wave * 32 + 16 + rowAdd) * K + kAdd;

  auto stageA = [&](int c2) {
    unsigned short* dst = sh + (c2 & 3) * 16384 + wave * 1024;  // shorts
    const long ko = (long)c2 * 32;
    async16(agA + ko, dst);
    async16(agA2 + ko, dst + 512);
  };
  auto stageB = [&](int c2) {
    unsigned short* dst = sh + (c2 & 3) * 16384 + 8192 + wave * 1024;
    const long ko = (long)c2 * 32;
    async16(bgB + ko, dst);
    async16(bgB2 + ko, dst + 512);
  };

  // ---- fragment read offsets (bytes within a slot region) ----
  // row = base + frag*16 + lidx -> L = base/2 + frag*8 + (lidx>>1), L&7 = lidx>>1
  const int cA = (((lane & 1) << 2) | quad) ^ ((lidx >> 1) & 7); // lane&1 == lidx&1
  const int aBase = (wr * 64 + (lidx >> 1)) * 128 + cA * 16;     // + mt*1024
  const int bBase = (wc * 32 + (lidx >> 1)) * 128 + cA * 16;     // + nt*1024 (region +16384B)

  // ---- prologue: 5 half-chunks ahead (chunks 0,1 full + A of 2) ----
  stageA(0); stageB(0);
  if (1 < NC) { stageA(1); stageB(1); }
  if (2 < NC) stageA(2);
  asm volatile("s_waitcnt vmcnt(6)" ::: "memory");   // chunk 0 (A+B) landed
  __builtin_amdgcn_sched_barrier(0);
  __builtin_amdgcn_s_barrier();
  __builtin_amdgcn_sched_barrier(0);

  for (int c = 0; c < NC; c++) {
    const char* sbase = (const char*)sh + (c & 3) * 32768;
    // ---------- sub-phase 0 ----------
    bf16x8_t bfr[4], af0[4];
#pragma unroll
    for (int nt = 0; nt < 4; nt++)
      bfr[nt] = *(const bf16x8_t*)(sbase + 16384 + bBase + nt * 1024);
#pragma unroll
    for (int mt = 0; mt < 4; mt++)
      af0[mt] = *(const bf16x8_t*)(sbase + aBase + mt * 1024);
    if (c + 2 < NC) stageB(c + 2);
    __builtin_amdgcn_s_barrier();
    asm volatile("s_waitcnt lgkmcnt(0)" ::: "memory");
    __builtin_amdgcn_sched_barrier(0);
    __builtin_amdgcn_s_setprio(1);
#pragma unroll
    for (int mt = 0; mt < 4; mt++)
#pragma unroll
      for (int nt = 0; nt < 4; nt++)
        acc[mt][nt] = __builtin_amdgcn_mfma_f32_16x16x32_bf16(af0[mt], bfr[nt], acc[mt][nt], 0, 0, 0);
    __builtin_amdgcn_s_setprio(0);
    __builtin_amdgcn_sched_barrier(0);
    __builtin_amdgcn_s_barrier();
    // ---------- sub-phase 1 ----------
    bf16x8_t af1[4];
#pragma unroll
    for (int mt = 0; mt < 4; mt++)
      af1[mt] = *(const bf16x8_t*)(sbase + aBase + 4096 + mt * 1024);
    if (c + 3 < NC) stageA(c + 3);
    __builtin_amdgcn_s_barrier();
    asm volatile("s_waitcnt lgkmcnt(0)" ::: "memory");
    __builtin_amdgcn_sched_barrier(0);
    __builtin_amdgcn_s_setprio(1);
#pragma unroll
    for (int mt = 0; mt < 4; mt++)
#pragma unroll
      for (int nt = 0; nt < 4; nt++)
        acc[mt + 4][nt] = __builtin_amdgcn_mfma_f32_16x16x32_bf16(af1[mt], bfr[nt], acc[mt + 4][nt], 0, 0, 0);
    __builtin_amdgcn_s_setprio(0);
    __builtin_amdgcn_sched_barrier(0);
    // ---------- chunk boundary: counted drain, then barrier ----------
    if (c + 1 < NC) {
      if (c + 1 <= NC - 3)      asm volatile("s_waitcnt vmcnt(6)" ::: "memory");
      else if (c + 1 == NC - 2) asm volatile("s_waitcnt vmcnt(4)" ::: "memory");
      else                      asm volatile("s_waitcnt vmcnt(0)" ::: "memory");
      __builtin_amdgcn_sched_barrier(0);
      __builtin_amdgcn_s_barrier();
      __builtin_amdgcn_sched_barrier(0);
    }
  }

  // ---------------- epilogues ----------------
  const int wrow = m0 + wr * 128;
  const int wcol = n0 + wc * 64;
  if (flags & 2) {
    // fused log-sum-exp partials: per wave, per row, reduce its 64-col strip
    const int pidx = blockIdx.y * 4 + wc;
#pragma unroll
    for (int mt = 0; mt < 8; mt++) {
#pragma unroll
      for (int r = 0; r < 4; r++) {
        const int row = wrow + mt * 16 + quad * 4 + r;
        float vals[4], m = -1e30f;
#pragma unroll
        for (int nt = 0; nt < 4; nt++) {
          const int colg = wcol + nt * 16 + lidx;
          float v = acc[mt][nt][r] + bias[colg];
          if (colg >= 21128) v = -1e30f;           // mask pad cols
          vals[nt] = v;
          m = fmaxf(m, v);
        }
#pragma unroll
        for (int o = 1; o < 16; o <<= 1) m = fmaxf(m, __shfl_xor(m, o, 16));
        float s = 0.f;
#pragma unroll
        for (int nt = 0; nt < 4; nt++) s += __expf(vals[nt] - m);
#pragma unroll
        for (int o = 1; o < 16; o <<= 1) s += __shfl_xor(s, o, 16);
        if (lidx == 0) { float2 p; p.x = m; p.y = s; st2[(long)pidx * 8192 + row] = p; }
        const int t = yv[row];
        const int yc = (t == -100) ? 0 : t;
#pragma unroll
        for (int nt = 0; nt < 4; nt++)
          if (wcol + nt * 16 + lidx == yc) tgt[row] = vals[nt];
      }
    }
    return;
  }

#pragma unroll
  for (int mt = 0; mt < 8; mt++) {
#pragma unroll
    for (int nt = 0; nt < 4; nt++) {
#pragma unroll
      for (int r = 0; r < 4; r++) {
        const int row = wrow + mt * 16 + quad * 4 + r;
        const int col = wcol + nt * 16 + lidx;
        float v = acc[mt][nt][r];
        if (bias) v += bias[col];
        if (flags & 1) v = 0.5f * v * (1.0f + erff(v * 0.70710678118f));
        const long o = (long)row * ldc + col;
        if (resid) v += resid[o];
        if (Cf) Cf[o] = v;
        if (Cb) Cb[o] = f2b(v);
      }
    }
  }
}

// ---------------- attention: per (qchunk, head, batch) block ----------------
__global__ __launch_bounds__(256, 2)
void attn_kernel(const unsigned short* __restrict__ qkv,   // [B*S][2304] = Q|K|V
                 unsigned short* __restrict__ ctx,         // [B*S][768]
                 const int* __restrict__ s1p)
{
  __shared__ unsigned short sh[32768];   // 64 KB: K [0,16384), V [16384,32768); P aliases K
  unsigned short* lK = sh;
  unsigned short* lV = sh + 16384;
  unsigned short* lP = sh;
  const int s1 = s1p[0];
  const int qc = blockIdx.x, h = blockIdx.y, b = blockIdx.z;
  const int tid = threadIdx.x;
  const int wave = tid >> 6, lane = tid & 63;
  const int quad = lane >> 4, lidx = lane & 15;
  const long tokbase = (long)b * 256 * 2304 + h * 64;

  {  // stage K,V with xor-swizzled 16B chunks (8 chunks per 64-wide row)
    const int kr = tid >> 3, c8 = tid & 7;
#pragma unroll
    for (int i = 0; i < 8; i++) {
      const int key = kr + i * 32;
      const unsigned short* src = qkv + tokbase + (long)key * 2304 + c8 * 8;
      const int sw = (c8 ^ (key & 7)) << 3;
      *(i32x4_t*)&lK[key * 64 + sw] = *(const i32x4_t*)(src + 768);
      *(i32x4_t*)&lV[key * 64 + sw] = *(const i32x4_t*)(src + 1536);
    }
  }
  bf16x8_t aq[2];
  {
    const int q = qc * 64 + wave * 16 + lidx;
    const unsigned short* qp = qkv + tokbase + (long)q * 2304;
    aq[0] = *(const bf16x8_t*)(qp + quad * 8);
    aq[1] = *(const bf16x8_t*)(qp + 32 + quad * 8);
  }
  __syncthreads();
  // QK^T: scores [16 q rows of this wave] x [256 keys]
  f32x4_t sc[16] = {};
#pragma unroll
  for (int kk = 0; kk < 2; kk++) {
#pragma unroll
    for (int nt = 0; nt < 16; nt++) {
      const int key = nt * 16 + lidx;
      const int ch = kk * 4 + quad;
      bf16x8_t bk = *(const bf16x8_t*)&lK[key * 64 + ((ch ^ (key & 7)) << 3)];
      sc[nt] = __builtin_amdgcn_mfma_f32_16x16x32_bf16(aq[kk], bk, sc[nt], 0, 0, 0);
    }
  }
  __syncthreads();   // all K reads done before P overwrites the same LDS
  const float scale = 0.125f;
  float rsum[4];
#pragma unroll
  for (int r = 0; r < 4; r++) {
    const int ql = wave * 16 + quad * 4 + r;
    const int q = qc * 64 + ql;
    float sv[16], m = -1e30f;
#pragma unroll
    for (int nt = 0; nt < 16; nt++) {
      const int key = nt * 16 + lidx;
      const float s = sc[nt][r] * scale + ((key < s1 || key <= q) ? 0.f : -1e9f);
      sv[nt] = s;
      m = fmaxf(m, s);
    }
#pragma unroll
    for (int o = 1; o < 16; o <<= 1) m = fmaxf(m, __shfl_xor(m, o, 16));
    float sum = 0.f;
#pragma unroll
    for (int nt = 0; nt < 16; nt++) {
      const float p = __expf(sv[nt] - m);
      sum += p;
      const int key = nt * 16 + lidx;
      lP[ql * 256 + ((((key >> 3) ^ (ql & 7))) << 3) + (key & 7)] = f2b(p);
    }
#pragma unroll
    for (int o = 1; o < 16; o <<= 1) sum += __shfl_xor(sum, o, 16);
    rsum[r] = sum;
  }
  __syncthreads();
  // PV: ctx[16 q][64 d] += P[16][256] x V[256][64]
  f32x4_t o4[4] = {};
#pragma unroll
  for (int kk = 0; kk < 8; kk++) {
    const int row = wave * 16 + lidx;
    const int ch = kk * 4 + quad;
    bf16x8_t ap = *(const bf16x8_t*)&lP[row * 256 + ((ch ^ (row & 7)) << 3)];
#pragma unroll
    for (int nt = 0; nt < 4; nt++) {
      bf16x8_t bv;
#pragma unroll
      for (int j = 0; j < 8; j++) {
        const int key = kk * 32 + quad * 8 + j;
        const int d = nt * 16 + lidx;
        bv[j] = (short)lV[key * 64 + (((d >> 3) ^ (key & 7)) << 3) + (d & 7)];
      }
      o4[nt] = __builtin_amdgcn_mfma_f32_16x16x32_bf16(ap, bv, o4[nt], 0, 0, 0);
    }
  }
#pragma unroll
  for (int nt = 0; nt < 4; nt++) {
#pragma unroll
    for (int r = 0; r < 4; r++) {
      const int q = qc * 64 + wave * 16 + quad * 4 + r;
      const int d = nt * 16 + lidx;
      ctx[(long)(b * 256 + q) * 768 + h * 64 + d] = f2b(o4[nt][r] / rsum[r]);
    }
  }
}

// ---------------- LayerNorm over H=768; writes f32 + bf16 ----------------
__global__ void ln_kernel(const float* __restrict__ in, const float* __restrict__ g,
                          const float* __restrict__ be, float* __restrict__ o32,
                          unsigned short* __restrict__ ob)
{
  __shared__ float sb1[4], sb2[4];
  const int row = blockIdx.x, tid = threadIdx.x;
  const float* x = in + (long)row * 768;
  float v[3], s = 0.f, ss = 0.f;
#pragma unroll
  for (int i = 0; i < 3; i++) { v[i] = x[tid + i * 256]; s += v[i]; ss += v[i] * v[i]; }
#pragma unroll
  for (int o = 32; o > 0; o >>= 1) { s += __shfl_down(s, o); ss += __shfl_down(ss, o); }
  if ((tid & 63) == 0) { sb1[tid >> 6] = s; sb2[tid >> 6] = ss; }
  __syncthreads();
  s = sb1[0] + sb1[1] + sb1[2] + sb1[3];
  ss = sb2[0] + sb2[1] + sb2[2] + sb2[3];
  const float mean = s * (1.f / 768.f);
  const float inv = rsqrtf(ss * (1.f / 768.f) - mean * mean + 1e-12f);
#pragma unroll
  for (int i = 0; i < 3; i++) {
    const int c = tid + i * 256;
    const float yv = (v[i] - mean) * inv * g[c] + be[c];
    if (o32) o32[(long)row * 768 + c] = yv;
    ob[(long)row * 768 + c] = f2b(yv);
  }
}

__global__ void embed_kernel(const int* __restrict__ xi, const float* __restrict__ we,
                             const float* __restrict__ pe, const float* __restrict__ te,
                             const float* __restrict__ g, const float* __restrict__ be,
                             float* __restrict__ o32, unsigned short* __restrict__ ob)
{
  __shared__ float sb1[4], sb2[4];
  const int row = blockIdx.x, tid = threadIdx.x;
  const int sidx = row & 255;
  const long id = xi[row];
  float v[3], s = 0.f, ss = 0.f;
#pragma unroll
  for (int i = 0; i < 3; i++) {
    const int c = tid + i * 256;
    v[i] = we[id * 768 + c] + pe[(long)sidx * 768 + c] + te[c];
    s += v[i]; ss += v[i] * v[i];
  }
#pragma unroll
  for (int o = 32; o > 0; o >>= 1) { s += __shfl_down(s, o); ss += __shfl_down(ss, o); }
  if ((tid & 63) == 0) { sb1[tid >> 6] = s; sb2[tid >> 6] = ss; }
  __syncthreads();
  s = sb1[0] + sb1[1] + sb1[2] + sb1[3];
  ss = sb2[0] + sb2[1] + sb2[2] + sb2[3];
  const float mean = s * (1.f / 768.f);
  const float inv = rsqrtf(ss * (1.f / 768.f) - mean * mean + 1e-12f);
#pragma unroll
  for (int i = 0; i < 3; i++) {
    const int c = tid + i * 256;
    const float yv = (v[i] - mean) * inv * g[c] + be[c];
    o32[(long)row * 768 + c] = yv;
    ob[(long)row * 768 + c] = f2b(yv);
  }
}

__global__ void zero2(float* p) { p[threadIdx.x] = 0.f; }

// merge the NPART per-column-strip (m,s) partials per row, then reduce the loss
__global__ void loss_final2(const float2* __restrict__ st2, const float* __restrict__ tgt,
                            const int* __restrict__ y, float* __restrict__ acc)
{
  __shared__ float sb1[4], sb2[4];
  const int tid = threadIdx.x;
  const int row = blockIdx.x * 256 + tid;
  float m = -1e30f, s = 0.f;
  for (int i = 0; i < NPART; i++) {
    const float2 p = st2[(long)i * 8192 + row];
    if (p.x > m) { s = s * __expf(m - p.x) + p.y; m = p.x; }
    else s += p.y * __expf(p.x - m);
  }
  const int t = y[row];
  float nll = 0.f, cv = 0.f;
  if (t != -100) {
    nll = m + __logf(s) - tgt[row];
    cv = 1.f;
  }
#pragma unroll
  for (int o = 32; o > 0; o >>= 1) { nll += __shfl_down(nll, o); cv += __shfl_down(cv, o); }
  if ((tid & 63) == 0) { sb1[tid >> 6] = nll; sb2[tid >> 6] = cv; }
  __syncthreads();
  if (tid == 0) {
    atomicAdd(&acc[0], sb1[0] + sb1[1] + sb1[2] + sb1[3]);
    atomicAdd(&acc[1], sb2[0] + sb2[1] + sb2[2] + sb2[3]);
  }
}
__global__ void loss_write(const float* __restrict__ acc, float* __restrict__ out)
{ out[0] = acc[0] / acc[1]; }

// ---------------- host launcher ----------------
extern "C" void kernel_launch(void* const* d_in, const int* in_sizes, int n_in,
                              void* d_out, int out_size, void* d_ws, size_t ws_size,
                              hipStream_t stream)
{
  const int* x = (const int*)d_in[0];
  const int* y = (const int*)d_in[1];
  const int* s1p = (const int*)d_in[2];
  const float* word = (const float*)d_in[4];
  const float* pos = (const float*)d_in[5];
  const float* typ = (const float*)d_in[6];
  const float* elg = (const float*)d_in[7];
  const float* elb = (const float*)d_in[8];
  const float* Wq = (const float*)d_in[9];
  const float* bq = (const float*)d_in[10];
  const float* Wk = (const float*)d_in[11];
  const float* bk = (const float*)d_in[12];
  const float* Wv = (const float*)d_in[13];
  const float* bvp = (const float*)d_in[14];
  const float* Wo = (const float*)d_in[15];
  const float* bo = (const float*)d_in[16];
  const float* l1g = (const float*)d_in[17];
  const float* l1b = (const float*)d_in[18];
  const float* W1 = (const float*)d_in[19];
  const float* b1 = (const float*)d_in[20];
  const float* W2 = (const float*)d_in[21];
  const float* b2 = (const float*)d_in[22];
  const float* l2g = (const float*)d_in[23];
  const float* l2b = (const float*)d_in[24];
  const float* cW = (const float*)d_in[25];
  const float* cb = (const float*)d_in[26];

  // allow 128 KiB dynamic LDS for the 8-phase GEMM (once per process)
  static int s_attr = 0;
  if (!s_attr) {
    hipFuncSetAttribute((const void*)gemm8p,
                        hipFuncAttributeMaxDynamicSharedMemorySize, 131072);
    s_attr = 1;
  }

  char* base = (char*)d_ws;
  size_t off = 0;
  auto alloc = [&](size_t bytes) -> void* {
    void* p = base + off;
    off = (off + bytes + 255) & ~(size_t)255;
    return p;
  };
  unsigned short* Wqkv = (unsigned short*)alloc(12ull * 2304 * 768 * 2);
  float* bqkv = (float*)alloc(12ull * 2304 * 4);
  unsigned short* Wot = (unsigned short*)alloc(12ull * 768 * 768 * 2);
  unsigned short* W1t = (unsigned short*)alloc(12ull * 3072 * 768 * 2);
  unsigned short* W2t = (unsigned short*)alloc(12ull * 768 * 3072 * 2);
  unsigned short* cWt = (unsigned short*)alloc(21248ull * 768 * 2);
  float* cbp = (float*)alloc(21248ull * 4);
  float* h32 = (float*)alloc(8192ull * 768 * 4);
  unsigned short* hb = (unsigned short*)alloc(8192ull * 768 * 2);
  unsigned short* qkvb = (unsigned short*)alloc(8192ull * 2304 * 2);
  unsigned short* ctxb = (unsigned short*)alloc(8192ull * 768 * 2);
  float* tmp32 = (float*)alloc(8192ull * 768 * 4);
  unsigned short* ffnb = (unsigned short*)alloc(8192ull * 3072 * 2);
  float2* st2 = (float2*)alloc((size_t)NPART * 8192 * 8);
  float* tgt = (float*)alloc(8192ull * 4);
  float* acc = (float*)alloc(256);

  const dim3 tt(32, 8);
  transpose_w<<<dim3(24, 24, 12), tt, 0, stream>>>(Wq, Wqkv, 768, 768, 768, 589824, 1769472);
  transpose_w<<<dim3(24, 24, 12), tt, 0, stream>>>(Wk, Wqkv + 589824, 768, 768, 768, 589824, 1769472);
  transpose_w<<<dim3(24, 24, 12), tt, 0, stream>>>(Wv, Wqkv + 1179648, 768, 768, 768, 589824, 1769472);
  transpose_w<<<dim3(24, 24, 12), tt, 0, stream>>>(Wo, Wot, 768, 768, 768, 589824, 589824);
  transpose_w<<<dim3(24, 96, 12), tt, 0, stream>>>(W1, W1t, 768, 3072, 3072, 2359296, 2359296);
  transpose_w<<<dim3(96, 24, 12), tt, 0, stream>>>(W2, W2t, 3072, 768, 768, 2359296, 2359296);
  transpose_w<<<dim3(24, 664, 1), tt, 0, stream>>>(cW, cWt, 768, 21128, 21248, 0, 0);
  build_bqkv<<<108, 256, 0, stream>>>(bq, bk, bvp, bqkv);
  build_clsb<<<83, 256, 0, stream>>>(cb, cbp);
  zero2<<<1, 2, 0, stream>>>(acc);

  embed_kernel<<<8192, 256, 0, stream>>>(x, word, pos, typ, elg, elb, h32, hb);

  for (int l = 0; l < 12; l++) {
    gemm8p<<<dim3(32, 9), 512, 131072, stream>>>(hb, Wqkv + (long)l * 1769472, bqkv + l * 2304,
                                                 nullptr, nullptr, qkvb, 768, 2304, 0,
                                                 nullptr, nullptr, nullptr);
    attn_kernel<<<dim3(4, 12, 32), 256, 0, stream>>>(qkvb, ctxb, s1p);
    gemm_db<64, 128><<<dim3(128, 6), 256, 0, stream>>>(ctxb, Wot + (long)l * 589824, bo + l * 768,
                                                       h32, tmp32, nullptr, 768, 768, 0,
                                                       nullptr, nullptr, nullptr);
    ln_kernel<<<8192, 256, 0, stream>>>(tmp32, l1g + l * 768, l1b + l * 768, h32, hb);
    gemm8p<<<dim3(32, 12), 512, 131072, stream>>>(hb, W1t + (long)l * 2359296, b1 + l * 3072,
                                                  nullptr, nullptr, ffnb, 768, 3072, 1,
                                                  nullptr, nullptr, nullptr);
    gemm_db<64, 128><<<dim3(128, 6), 256, 0, stream>>>(ffnb, W2t + (long)l * 2359296, b2 + l * 768,
                                                       h32, tmp32, nullptr, 3072, 768, 0,
                                                       nullptr, nullptr, nullptr);
    ln_kernel<<<8192, 256, 0, stream>>>(tmp32, l2g + l * 768, l2b + l * 768, h32, hb);
  }

  // classifier + fused LSE: one dispatch over all 21248 (padded) columns
  gemm8p<<<dim3(32, 83), 512, 131072, stream>>>(hb, cWt, cbp,
                                                nullptr, nullptr, nullptr,
                                                768, 0, 2, y, st2, tgt);
  loss_final2<<<32, 256, 0, stream>>>(st2, tgt, y, acc);
  loss_write<<<1, 1, 0, stream>>>(acc, (float*)d_out);
}

// Round 2
// 5168.310 us; speedup vs baseline: 1.0926x; 1.0926x over previous
//
#include <hip/hip_runtime.h>

typedef __attribute__((ext_vector_type(8))) short bf16x8_t;
typedef __attribute__((ext_vector_type(4))) float f32x4_t;
typedef __attribute__((ext_vector_type(4))) int i32x4_t;

#define NPART 332   // 21248/64 column-strip partials for the classifier LSE

__device__ __forceinline__ unsigned short f2b(float f) {
  unsigned int u = __builtin_bit_cast(unsigned int, f);
  u += 0x7fffu + ((u >> 16) & 1u);
  return (unsigned short)(u >> 16);
}
__device__ __forceinline__ float b2f(unsigned short h) {
  unsigned int u = ((unsigned int)h) << 16;
  return __builtin_bit_cast(float, u);
}

// async global->LDS, 16B per lane; LDS dest is wave-uniform base + lane*16
__device__ __forceinline__ void async16(const unsigned short* g, unsigned short* l) {
  __builtin_amdgcn_global_load_lds(
      (const __attribute__((address_space(1))) unsigned int*)g,
      (__attribute__((address_space(3))) unsigned int*)l, 16, 0, 0);
}

// ---------------- transpose+convert: in f32 [K][N] -> out bf16 [Npad][K] ----------------
__global__ void transpose_w(const float* __restrict__ in, unsigned short* __restrict__ out,
                            int K, int N, int Npad, long inBatch, long outBatch)
{
  __shared__ float tile[32][33];
  const int bz = blockIdx.z;
  in += (long)bz * inBatch;
  out += (long)bz * outBatch;
  const int k0 = blockIdx.x * 32, n0 = blockIdx.y * 32;
  const int tx = threadIdx.x, ty = threadIdx.y;  // 32 x 8
#pragma unroll
  for (int i = 0; i < 32; i += 8) {
    const int k = k0 + ty + i, n = n0 + tx;
    tile[ty + i][tx] = (k < K && n < N) ? in[(long)k * N + n] : 0.f;
  }
  __syncthreads();
#pragma unroll
  for (int i = 0; i < 32; i += 8) {
    const int n = n0 + ty + i, k = k0 + tx;
    if (n < Npad && k < K) out[(long)n * K + k] = f2b(tile[tx][ty + i]);
  }
}

__global__ void build_bqkv(const float* __restrict__ bq, const float* __restrict__ bk,
                           const float* __restrict__ bv, float* __restrict__ out)
{
  const int i = blockIdx.x * 256 + threadIdx.x;
  if (i >= 12 * 2304) return;
  const int l = i / 2304, j = i % 2304;
  float v;
  if (j < 768) v = bq[l * 768 + j];
  else if (j < 1536) v = bk[l * 768 + j - 768];
  else v = bv[l * 768 + j - 1536];
  out[i] = v;
}
__global__ void build_clsb(const float* __restrict__ cb, float* __restrict__ out)
{
  const int i = blockIdx.x * 256 + threadIdx.x;
  if (i < 21248) out[i] = (i < 21128) ? cb[i] : 0.f;
}

// ---------------- counted-vmcnt pipelined GEMM: C[M][N] = A[M][K] x Bt[N][K] (bf16) ----------------
// 128x128 tile, 4 waves (per-wave 64x64, acc[4][4]), BK=32 chunks through 3
// rotating LDS slots (48 KiB) -> 3 blocks/CU (12 waves). One raw s_barrier per
// chunk; vmcnt(4) counted drain (stage lead = 2 chunks), vmcnt(0) only at tail.
// Slot layout is linear (64B rows, 4x16B chunks): fragment ds_read_b128 is
// bank-uniform (every bank serves exactly 8 dwords = floor), no swizzle needed,
// and global_load_lds' linear dest matches (G21 both-sides-or-neither).
// flags: 1 = gelu, 2 = fused log-sum-exp epilogue (classifier; no C store)
__global__ __launch_bounds__(256, 3)
void gemm_cnt(const unsigned short* __restrict__ A,
              const unsigned short* __restrict__ Bt,
              const float* __restrict__ bias,
              const float* __restrict__ resid,
              float* __restrict__ Cf,
              unsigned short* __restrict__ Cb,
              int K, int ldc, int flags,
              const int* __restrict__ yv, float2* __restrict__ st2,
              float* __restrict__ tgt)
{
  __shared__ unsigned short sh[3 * 8192];   // 3 slots x (A 128x32 | B 128x32) = 48 KiB
  const int tid = threadIdx.x;
  const int wave = tid >> 6, lane = tid & 63;
  const int quad = lane >> 4, lidx = lane & 15;
  const int m0 = blockIdx.x * 128, n0 = blockIdx.y * 128;
  const int wm = (wave >> 1) * 64, wn = (wave & 1) * 64;
  const int NC = K >> 5;                    // 32-wide K chunks; K % 32 == 0
  f32x4_t acc[4][4] = {};

  // staging: lane -> row (lane>>2) within a 16-row group, 16B k-chunk (lane&3)
  const int srow = lane >> 2, sch = (lane & 3) * 8;
  const unsigned short* ag = A + (long)(m0 + wave * 32 + srow) * K + sch;
  const unsigned short* bg = Bt + (long)(n0 + wave * 32 + srow) * K + sch;
  const int adst = (wave * 32) * 32;        // shorts; wave stages rows 32w..32w+31
  const int bdst = 4096 + (wave * 32) * 32;

  auto stage = [&](int c, int slot) {
    unsigned short* s = sh + slot * 8192;
    const long ko = (long)c * 32;
    async16(ag + ko, s + adst);
    async16(ag + (long)16 * K + ko, s + adst + 512);
    async16(bg + ko, s + bdst);
    async16(bg + (long)16 * K + ko, s + bdst + 512);
  };

  // prologue: chunks 0,1 in flight; wait chunk 0 (allow chunk 1's 4 loads)
  stage(0, 0);
  stage(1, 1);
  asm volatile("s_waitcnt vmcnt(4)" ::: "memory");
  __builtin_amdgcn_s_barrier();
  __builtin_amdgcn_sched_barrier(0);

  int sl = 0, st = 2;
  for (int c = 0; c < NC; c++) {
    const unsigned short* lA = sh + sl * 8192;
    const unsigned short* lB = lA + 4096;
    bf16x8_t af[4], bf[4];
#pragma unroll
    for (int t = 0; t < 4; t++)
      af[t] = *(const bf16x8_t*)&lA[(wm + t * 16 + lidx) * 32 + quad * 8];
#pragma unroll
    for (int t = 0; t < 4; t++)
      bf[t] = *(const bf16x8_t*)&lB[(wn + t * 16 + lidx) * 32 + quad * 8];
    if (c + 2 < NC) stage(c + 2, st);       // 2-chunk lead into the free slot
    __builtin_amdgcn_s_setprio(1);
#pragma unroll
    for (int mt = 0; mt < 4; mt++)
#pragma unroll
      for (int nt = 0; nt < 4; nt++)
        acc[mt][nt] = __builtin_amdgcn_mfma_f32_16x16x32_bf16(af[mt], bf[nt], acc[mt][nt], 0, 0, 0);
    __builtin_amdgcn_s_setprio(0);
    // chunk boundary: ensure chunk c+1 landed (own slice via vmcnt, others via barrier)
    if (c + 1 < NC) {
      if (c + 2 < NC) asm volatile("s_waitcnt vmcnt(4)" ::: "memory");
      else            asm volatile("s_waitcnt vmcnt(0)" ::: "memory");
      __builtin_amdgcn_s_barrier();
      __builtin_amdgcn_sched_barrier(0);
    }
    sl = (sl == 2) ? 0 : sl + 1;
    st = (st == 2) ? 0 : st + 1;
  }

  // ---------------- epilogues ----------------
  if (flags & 2) {
    // fused log-sum-exp partials: per wave, per row, reduce its 64-col strip
    const int pidx = blockIdx.y * 2 + (wave & 1);
#pragma unroll
    for (int mt = 0; mt < 4; mt++) {
#pragma unroll
      for (int r = 0; r < 4; r++) {
        const int row = m0 + wm + mt * 16 + quad * 4 + r;
        float vals[4], m = -1e30f;
#pragma unroll
        for (int nt = 0; nt < 4; nt++) {
          const int colg = n0 + wn + nt * 16 + lidx;
          float v = acc[mt][nt][r] + bias[colg];
          if (colg >= 21128) v = -1e30f;           // mask pad cols
          vals[nt] = v;
          m = fmaxf(m, v);
        }
#pragma unroll
        for (int o = 1; o < 16; o <<= 1) m = fmaxf(m, __shfl_xor(m, o, 16));
        float s = 0.f;
#pragma unroll
        for (int nt = 0; nt < 4; nt++) s += __expf(vals[nt] - m);
#pragma unroll
        for (int o = 1; o < 16; o <<= 1) s += __shfl_xor(s, o, 16);
        if (lidx == 0) { float2 p; p.x = m; p.y = s; st2[(long)pidx * 8192 + row] = p; }
        const int t = yv[row];
        const int yc = (t == -100) ? 0 : t;
#pragma unroll
        for (int nt = 0; nt < 4; nt++)
          if (n0 + wn + nt * 16 + lidx == yc) tgt[row] = vals[nt];
      }
    }
    return;
  }

#pragma unroll
  for (int mt = 0; mt < 4; mt++) {
#pragma unroll
    for (int nt = 0; nt < 4; nt++) {
#pragma unroll
      for (int r = 0; r < 4; r++) {
        const int row = m0 + wm + mt * 16 + quad * 4 + r;
        const int col = n0 + wn + nt * 16 + lidx;
        float v = acc[mt][nt][r];
        if (bias) v += bias[col];
        if (flags & 1) v = 0.5f * v * (1.0f + erff(v * 0.70710678118f));
        const long o = (long)row * ldc + col;
        if (resid) v += resid[o];
        if (Cf) Cf[o] = v;
        if (Cb) Cb[o] = f2b(v);
      }
    }
  }
}

// ---------------- attention: per (qchunk, head, batch) block ----------------
__global__ __launch_bounds__(256, 2)
void attn_kernel(const unsigned short* __restrict__ qkv,   // [B*S][2304] = Q|K|V
                 unsigned short* __restrict__ ctx,         // [B*S][768]
                 const int* __restrict__ s1p)
{
  __shared__ unsigned short sh[32768];   // 64 KB: K [0,16384), V [16384,32768); P aliases K
  unsigned short* lK = sh;
  unsigned short* lV = sh + 16384;
  unsigned short* lP = sh;
  const int s1 = s1p[0];
  const int qc = blockIdx.x, h = blockIdx.y, b = blockIdx.z;
  const int tid = threadIdx.x;
  const int wave = tid >> 6, lane = tid & 63;
  const int quad = lane >> 4, lidx = lane & 15;
  const long tokbase = (long)b * 256 * 2304 + h * 64;

  {  // stage K,V with xor-swizzled 16B chunks (8 chunks per 64-wide row)
    const int kr = tid >> 3, c8 = tid & 7;
#pragma unroll
    for (int i = 0; i < 8; i++) {
      const int key = kr + i * 32;
      const unsigned short* src = qkv + tokbase + (long)key * 2304 + c8 * 8;
      const int sw = (c8 ^ (key & 7)) << 3;
      *(i32x4_t*)&lK[key * 64 + sw] = *(const i32x4_t*)(src + 768);
      *(i32x4_t*)&lV[key * 64 + sw] = *(const i32x4_t*)(src + 1536);
    }
  }
  bf16x8_t aq[2];
  {
    const int q = qc * 64 + wave * 16 + lidx;
    const unsigned short* qp = qkv + tokbase + (long)q * 2304;
    aq[0] = *(const bf16x8_t*)(qp + quad * 8);
    aq[1] = *(const bf16x8_t*)(qp + 32 + quad * 8);
  }
  __syncthreads();
  // QK^T: scores [16 q rows of this wave] x [256 keys]
  f32x4_t sc[16] = {};
#pragma unroll
  for (int kk = 0; kk < 2; kk++) {
#pragma unroll
    for (int nt = 0; nt < 16; nt++) {
      const int key = nt * 16 + lidx;
      const int ch = kk * 4 + quad;
      bf16x8_t bk = *(const bf16x8_t*)&lK[key * 64 + ((ch ^ (key & 7)) << 3)];
      sc[nt] = __builtin_amdgcn_mfma_f32_16x16x32_bf16(aq[kk], bk, sc[nt], 0, 0, 0);
    }
  }
  __syncthreads();   // all K reads done before P overwrites the same LDS
  const float scale = 0.125f;
  float rsum[4];
#pragma unroll
  for (int r = 0; r < 4; r++) {
    const int ql = wave * 16 + quad * 4 + r;
    const int q = qc * 64 + ql;
    float sv[16], m = -1e30f;
#pragma unroll
    for (int nt = 0; nt < 16; nt++) {
      const int key = nt * 16 + lidx;
      const float s = sc[nt][r] * scale + ((key < s1 || key <= q) ? 0.f : -1e9f);
      sv[nt] = s;
      m = fmaxf(m, s);
    }
#pragma unroll
    for (int o = 1; o < 16; o <<= 1) m = fmaxf(m, __shfl_xor(m, o, 16));
    float sum = 0.f;
#pragma unroll
    for (int nt = 0; nt < 16; nt++) {
      const float p = __expf(sv[nt] - m);
      sum += p;
      const int key = nt * 16 + lidx;
      lP[ql * 256 + ((((key >> 3) ^ (ql & 7))) << 3) + (key & 7)] = f2b(p);
    }
#pragma unroll
    for (int o = 1; o < 16; o <<= 1) sum += __shfl_xor(sum, o, 16);
    rsum[r] = sum;
  }
  __syncthreads();
  // PV: ctx[16 q][64 d] += P[16][256] x V[256][64]
  f32x4_t o4[4] = {};
#pragma unroll
  for (int kk = 0; kk < 8; kk++) {
    const int row = wave * 16 + lidx;
    const int ch = kk * 4 + quad;
    bf16x8_t ap = *(const bf16x8_t*)&lP[row * 256 + ((ch ^ (row & 7)) << 3)];
#pragma unroll
    for (int nt = 0; nt < 4; nt++) {
      bf16x8_t bv;
#pragma unroll
      for (int j = 0; j < 8; j++) {
        const int key = kk * 32 + quad * 8 + j;
        const int d = nt * 16 + lidx;
        bv[j] = (short)lV[key * 64 + (((d >> 3) ^ (key & 7)) << 3) + (d & 7)];
      }
      o4[nt] = __builtin_amdgcn_mfma_f32_16x16x32_bf16(ap, bv, o4[nt], 0, 0, 0);
    }
  }
#pragma unroll
  for (int nt = 0; nt < 4; nt++) {
#pragma unroll
    for (int r = 0; r < 4; r++) {
      const int q = qc * 64 + wave * 16 + quad * 4 + r;
      const int d = nt * 16 + lidx;
      ctx[(long)(b * 256 + q) * 768 + h * 64 + d] = f2b(o4[nt][r] / rsum[r]);
    }
  }
}

// ---------------- LayerNorm over H=768; writes f32 + bf16 ----------------
__global__ void ln_kernel(const float* __restrict__ in, const float* __restrict__ g,
                          const float* __restrict__ be, float* __restrict__ o32,
                          unsigned short* __restrict__ ob)
{
  __shared__ float sb1[4], sb2[4];
  const int row = blockIdx.x, tid = threadIdx.x;
  const float* x = in + (long)row * 768;
  float v[3], s = 0.f, ss = 0.f;
#pragma unroll
  for (int i = 0; i < 3; i++) { v[i] = x[tid + i * 256]; s += v[i]; ss += v[i] * v[i]; }
#pragma unroll
  for (int o = 32; o > 0; o >>= 1) { s += __shfl_down(s, o); ss += __shfl_down(ss, o); }
  if ((tid & 63) == 0) { sb1[tid >> 6] = s; sb2[tid >> 6] = ss; }
  __syncthreads();
  s = sb1[0] + sb1[1] + sb1[2] + sb1[3];
  ss = sb2[0] + sb2[1] + sb2[2] + sb2[3];
  const float mean = s * (1.f / 768.f);
  const float inv = rsqrtf(ss * (1.f / 768.f) - mean * mean + 1e-12f);
#pragma unroll
  for (int i = 0; i < 3; i++) {
    const int c = tid + i * 256;
    const float yv = (v[i] - mean) * inv * g[c] + be[c];
    if (o32) o32[(long)row * 768 + c] = yv;
    ob[(long)row * 768 + c] = f2b(yv);
  }
}

__global__ void embed_kernel(const int* __restrict__ xi, const float* __restrict__ we,
                             const float* __restrict__ pe, const float* __restrict__ te,
                             const float* __restrict__ g, const float* __restrict__ be,
                             float* __restrict__ o32, unsigned short* __restrict__ ob)
{
  __shared__ float sb1[4], sb2[4];
  const int row = blockIdx.x, tid = threadIdx.x;
  const int sidx = row & 255;
  const long id = xi[row];
  float v[3], s = 0.f, ss = 0.f;
#pragma unroll
  for (int i = 0; i < 3; i++) {
    const int c = tid + i * 256;
    v[i] = we[id * 768 + c] + pe[(long)sidx * 768 + c] + te[c];
    s += v[i]; ss += v[i] * v[i];
  }
#pragma unroll
  for (int o = 32; o > 0; o >>= 1) { s += __shfl_down(s, o); ss += __shfl_down(ss, o); }
  if ((tid & 63) == 0) { sb1[tid >> 6] = s; sb2[tid >> 6] = ss; }
  __syncthreads();
  s = sb1[0] + sb1[1] + sb1[2] + sb1[3];
  ss = sb2[0] + sb2[1] + sb2[2] + sb2[3];
  const float mean = s * (1.f / 768.f);
  const float inv = rsqrtf(ss * (1.f / 768.f) - mean * mean + 1e-12f);
#pragma unroll
  for (int i = 0; i < 3; i++) {
    const int c = tid + i * 256;
    const float yv = (v[i] - mean) * inv * g[c] + be[c];
    o32[(long)row * 768 + c] = yv;
    ob[(long)row * 768 + c] = f2b(yv);
  }
}

__global__ void zero2(float* p) { p[threadIdx.x] = 0.f; }

// merge the NPART per-column-strip (m,s) partials per row, then reduce the loss
__global__ void loss_final2(const float2* __restrict__ st2, const float* __restrict__ tgt,
                            const int* __restrict__ y, float* __restrict__ acc)
{
  __shared__ float sb1[4], sb2[4];
  const int tid = threadIdx.x;
  const int row = blockIdx.x * 256 + tid;
  float m = -1e30f, s = 0.f;
  for (int i = 0; i < NPART; i++) {
    const float2 p = st2[(long)i * 8192 + row];
    if (p.x > m) { s = s * __expf(m - p.x) + p.y; m = p.x; }
    else s += p.y * __expf(p.x - m);
  }
  const int t = y[row];
  float nll = 0.f, cv = 0.f;
  if (t != -100) {
    nll = m + __logf(s) - tgt[row];
    cv = 1.f;
  }
#pragma unroll
  for (int o = 32; o > 0; o >>= 1) { nll += __shfl_down(nll, o); cv += __shfl_down(cv, o); }
  if ((tid & 63) == 0) { sb1[tid >> 6] = nll; sb2[tid >> 6] = cv; }
  __syncthreads();
  if (tid == 0) {
    atomicAdd(&acc[0], sb1[0] + sb1[1] + sb1[2] + sb1[3]);
    atomicAdd(&acc[1], sb2[0] + sb2[1] + sb2[2] + sb2[3]);
  }
}
__global__ void loss_write(const float* __restrict__ acc, float* __restrict__ out)
{ out[0] = acc[0] / acc[1]; }

// ---------------- host launcher ----------------
extern "C" void kernel_launch(void* const* d_in, const int* in_sizes, int n_in,
                              void* d_out, int out_size, void* d_ws, size_t ws_size,
                              hipStream_t stream)
{
  const int* x = (const int*)d_in[0];
  const int* y = (const int*)d_in[1];
  const int* s1p = (const int*)d_in[2];
  const float* word = (const float*)d_in[4];
  const float* pos = (const float*)d_in[5];
  const float* typ = (const float*)d_in[6];
  const float* elg = (const float*)d_in[7];
  const float* elb = (const float*)d_in[8];
  const float* Wq = (const float*)d_in[9];
  const float* bq = (const float*)d_in[10];
  const float* Wk = (const float*)d_in[11];
  const float* bk = (const float*)d_in[12];
  const float* Wv = (const float*)d_in[13];
  const float* bvp = (const float*)d_in[14];
  const float* Wo = (const float*)d_in[15];
  const float* bo = (const float*)d_in[16];
  const float* l1g = (const float*)d_in[17];
  const float* l1b = (const float*)d_in[18];
  const float* W1 = (const float*)d_in[19];
  const float* b1 = (const float*)d_in[20];
  const float* W2 = (const float*)d_in[21];
  const float* b2 = (const float*)d_in[22];
  const float* l2g = (const float*)d_in[23];
  const float* l2b = (const float*)d_in[24];
  const float* cW = (const float*)d_in[25];
  const float* cb = (const float*)d_in[26];

  char* base = (char*)d_ws;
  size_t off = 0;
  auto alloc = [&](size_t bytes) -> void* {
    void* p = base + off;
    off = (off + bytes + 255) & ~(size_t)255;
    return p;
  };
  unsigned short* Wqkv = (unsigned short*)alloc(12ull * 2304 * 768 * 2);
  float* bqkv = (float*)alloc(12ull * 2304 * 4);
  unsigned short* Wot = (unsigned short*)alloc(12ull * 768 * 768 * 2);
  unsigned short* W1t = (unsigned short*)alloc(12ull * 3072 * 768 * 2);
  unsigned short* W2t = (unsigned short*)alloc(12ull * 768 * 3072 * 2);
  unsigned short* cWt = (unsigned short*)alloc(21248ull * 768 * 2);
  float* cbp = (float*)alloc(21248ull * 4);
  float* h32 = (float*)alloc(8192ull * 768 * 4);
  unsigned short* hb = (unsigned short*)alloc(8192ull * 768 * 2);
  unsigned short* qkvb = (unsigned short*)alloc(8192ull * 2304 * 2);
  unsigned short* ctxb = (unsigned short*)alloc(8192ull * 768 * 2);
  float* tmp32 = (float*)alloc(8192ull * 768 * 4);
  unsigned short* ffnb = (unsigned short*)alloc(8192ull * 3072 * 2);
  float2* st2 = (float2*)alloc((size_t)NPART * 8192 * 8);
  float* tgt = (float*)alloc(8192ull * 4);
  float* acc = (float*)alloc(256);

  const dim3 tt(32, 8);
  transpose_w<<<dim3(24, 24, 12), tt, 0, stream>>>(Wq, Wqkv, 768, 768, 768, 589824, 1769472);
  transpose_w<<<dim3(24, 24, 12), tt, 0, stream>>>(Wk, Wqkv + 589824, 768, 768, 768, 589824, 1769472);
  transpose_w<<<dim3(24, 24, 12), tt, 0, stream>>>(Wv, Wqkv + 1179648, 768, 768, 768, 589824, 1769472);
  transpose_w<<<dim3(24, 24, 12), tt, 0, stream>>>(Wo, Wot, 768, 768, 768, 589824, 589824);
  transpose_w<<<dim3(24, 96, 12), tt, 0, stream>>>(W1, W1t, 768, 3072, 3072, 2359296, 2359296);
  transpose_w<<<dim3(96, 24, 12), tt, 0, stream>>>(W2, W2t, 3072, 768, 768, 2359296, 2359296);
  transpose_w<<<dim3(24, 664, 1), tt, 0, stream>>>(cW, cWt, 768, 21128, 21248, 0, 0);
  build_bqkv<<<108, 256, 0, stream>>>(bq, bk, bvp, bqkv);
  build_clsb<<<83, 256, 0, stream>>>(cb, cbp);
  zero2<<<1, 2, 0, stream>>>(acc);

  embed_kernel<<<8192, 256, 0, stream>>>(x, word, pos, typ, elg, elb, h32, hb);

  for (int l = 0; l < 12; l++) {
    gemm_cnt<<<dim3(64, 18), 256, 0, stream>>>(hb, Wqkv + (long)l * 1769472, bqkv + l * 2304,
                                               nullptr, nullptr, qkvb, 768, 2304, 0,
                                               nullptr, nullptr, nullptr);
    attn_kernel<<<dim3(4, 12, 32), 256, 0, stream>>>(qkvb, ctxb, s1p);
    gemm_cnt<<<dim3(64, 6), 256, 0, stream>>>(ctxb, Wot + (long)l * 589824, bo + l * 768,
                                              h32, tmp32, nullptr, 768, 768, 0,
                                              nullptr, nullptr, nullptr);
    ln_kernel<<<8192, 256, 0, stream>>>(tmp32, l1g + l * 768, l1b + l * 768, h32, hb);
    gemm_cnt<<<dim3(64, 24), 256, 0, stream>>>(hb, W1t + (long)l * 2359296, b1 + l * 3072,
                                               nullptr, nullptr, ffnb, 768, 3072, 1,
                                               nullptr, nullptr, nullptr);
    gemm_cnt<<<dim3(64, 6), 256, 0, stream>>>(ffnb, W2t + (long)l * 2359296, b2 + l * 768,
                                              h32, tmp32, nullptr, 3072, 768, 0,
                                              nullptr, nullptr, nullptr);
    ln_kernel<<<8192, 256, 0, stream>>>(tmp32, l2g + l * 768, l2b + l * 768, h32, hb);
  }

  // classifier + fused LSE: one dispatch over all 21248 (padded) columns
  gemm_cnt<<<dim3(64, 166), 256, 0, stream>>>(hb, cWt, cbp,
                                              nullptr, nullptr, nullptr,
                                              768, 0, 2, y, st2, tgt);
  loss_final2<<<32, 256, 0, stream>>>(st2, tgt, y, acc);
  loss_write<<<1, 1, 0, stream>>>(acc, (float*)d_out);
}

// Round 3
// 5060.400 us; speedup vs baseline: 1.1159x; 1.0213x over previous
//
#include <hip/hip_runtime.h>

typedef __attribute__((ext_vector_type(8))) short bf16x8_t;
typedef __attribute__((ext_vector_type(4))) float f32x4_t;
typedef __attribute__((ext_vector_type(4))) int i32x4_t;

#define NPART 332   // 21248/64 column-strip partials for the classifier LSE

__device__ __forceinline__ unsigned short f2b(float f) {
  unsigned int u = __builtin_bit_cast(unsigned int, f);
  u += 0x7fffu + ((u >> 16) & 1u);
  return (unsigned short)(u >> 16);
}
__device__ __forceinline__ float b2f(unsigned short h) {
  unsigned int u = ((unsigned int)h) << 16;
  return __builtin_bit_cast(float, u);
}

// async global->LDS, 16B per lane; LDS dest is wave-uniform base + lane*16
__device__ __forceinline__ void async16(const unsigned short* g, unsigned short* l) {
  __builtin_amdgcn_global_load_lds(
      (const __attribute__((address_space(1))) unsigned int*)g,
      (__attribute__((address_space(3))) unsigned int*)l, 16, 0, 0);
}

// ---------------- transpose+convert: in f32 [K][N] -> out bf16 [Npad][K] ----------------
__global__ void transpose_w(const float* __restrict__ in, unsigned short* __restrict__ out,
                            int K, int N, int Npad, long inBatch, long outBatch)
{
  __shared__ float tile[32][33];
  const int bz = blockIdx.z;
  in += (long)bz * inBatch;
  out += (long)bz * outBatch;
  const int k0 = blockIdx.x * 32, n0 = blockIdx.y * 32;
  const int tx = threadIdx.x, ty = threadIdx.y;  // 32 x 8
#pragma unroll
  for (int i = 0; i < 32; i += 8) {
    const int k = k0 + ty + i, n = n0 + tx;
    tile[ty + i][tx] = (k < K && n < N) ? in[(long)k * N + n] : 0.f;
  }
  __syncthreads();
#pragma unroll
  for (int i = 0; i < 32; i += 8) {
    const int n = n0 + ty + i, k = k0 + tx;
    if (n < Npad && k < K) out[(long)n * K + k] = f2b(tile[tx][ty + i]);
  }
}

__global__ void build_bqkv(const float* __restrict__ bq, const float* __restrict__ bk,
                           const float* __restrict__ bv, float* __restrict__ out)
{
  const int i = blockIdx.x * 256 + threadIdx.x;
  if (i >= 12 * 2304) return;
  const int l = i / 2304, j = i % 2304;
  float v;
  if (j < 768) v = bq[l * 768 + j];
  else if (j < 1536) v = bk[l * 768 + j - 768];
  else v = bv[l * 768 + j - 1536];
  out[i] = v;
}
__global__ void build_clsb(const float* __restrict__ cb, float* __restrict__ out)
{
  const int i = blockIdx.x * 256 + threadIdx.x;
  if (i < 21248) out[i] = (i < 21128) ? cb[i] : 0.f;
}

// ---------------- counted-vmcnt pipelined GEMM: C[M][N] = A[M][K] x Bt[N][K] (bf16) ----------------
// TMxTN tile, 4 waves, BK=32 chunks through 3 rotating LDS slots -> 3 blocks/CU.
// One raw s_barrier per chunk; vmcnt(LPC) counted drain, vmcnt(0) only at tail.
//
// LDS slot layout (both A and B regions): 64B rows of 4 x 16B chunks; chunk c of
// row r stored at slot position c ^ ((r>>1)&3).  Fragment ds_read_b128 then hits
// each of the 8 bank-groups exactly twice per quarter-wave (2-addr floor =
// conflict-free).  global_load_lds writes LINEARLY (lane*16B); the per-lane
// GLOBAL source applies the inverse permutation, so write+read swizzles match
// (G21 both-sides-or-neither) and 64B-row coalescing is preserved.
// flags: 1 = gelu, 2 = fused log-sum-exp epilogue (classifier; no C store)
template <int TM, int TN>
__global__ __launch_bounds__(256, 3)
void gemm_cnt(const unsigned short* __restrict__ A,
              const unsigned short* __restrict__ Bt,
              const float* __restrict__ bias,
              const float* __restrict__ resid,
              float* __restrict__ Cf,
              unsigned short* __restrict__ Cb,
              int K, int ldc, int flags,
              const int* __restrict__ yv, float2* __restrict__ st2,
              float* __restrict__ tgt)
{
  constexpr int WCOLS = (TM == 128) ? 2 : 4;   // wave grid: (4/WCOLS) x WCOLS
  constexpr int WN = TN / WCOLS;               // per-wave N (64 or 32)
  constexpr int NT = WN / 16;
  constexpr int GA = TM / 64, GB = TN / 64;    // 16-row stage groups per wave
  constexpr int LPC = GA + GB;                 // global_load_lds per wave per chunk
  constexpr int SLOT = (TM + TN) * 32;         // shorts per slot
  __shared__ unsigned short sh[3 * SLOT];
  const int tid = threadIdx.x;
  const int wave = tid >> 6, lane = tid & 63;
  const int quad = lane >> 4, lidx = lane & 15;
  const int m0 = blockIdx.x * TM, n0 = blockIdx.y * TN;
  const int wm = (wave / WCOLS) * 64, wn = (wave % WCOLS) * WN;
  const int NC = K >> 5;                       // 32-wide K chunks; K % 32 == 0
  f32x4_t acc[4][NT] = {};

  // staging: lane covers row (lane>>2) of its 16-row group; source 16B chunk is
  // the inverse swizzle c = (lane&3) ^ ((row>>1)&3), row>>1 bits = lane>>3
  const int srow = lane >> 2;
  const int sch = ((lane & 3) ^ ((lane >> 3) & 3)) * 8;
  const unsigned short* ag = A + (long)(m0 + wave * (TM / 4) + srow) * K + sch;
  const unsigned short* bg = Bt + (long)(n0 + wave * (TN / 4) + srow) * K + sch;
  const int adst = wave * (TM / 4) * 32;       // shorts
  const int bdst = TM * 32 + wave * (TN / 4) * 32;

  auto stage = [&](int c, int slot) {
    unsigned short* s = sh + slot * SLOT;
    const long ko = (long)c * 32;
#pragma unroll
    for (int g = 0; g < GA; g++) async16(ag + (long)(g * 16) * K + ko, s + adst + g * 512);
#pragma unroll
    for (int g = 0; g < GB; g++) async16(bg + (long)(g * 16) * K + ko, s + bdst + g * 512);
  };

  // prologue: chunks 0,1 in flight; wait chunk 0 (allow chunk 1's LPC loads)
  stage(0, 0);
  stage(1, 1);
  if constexpr (LPC == 4) asm volatile("s_waitcnt vmcnt(4)" ::: "memory");
  else                    asm volatile("s_waitcnt vmcnt(3)" ::: "memory");
  __builtin_amdgcn_s_barrier();
  __builtin_amdgcn_sched_barrier(0);

  const int rsw = (quad ^ ((lidx >> 1) & 3)) * 8;  // read-side chunk swizzle (elems)
  int sl = 0, st = 2;
  for (int c = 0; c < NC; c++) {
    const unsigned short* lA = sh + sl * SLOT;
    const unsigned short* lB = lA + TM * 32;
    bf16x8_t af[4], bf[NT];
#pragma unroll
    for (int t = 0; t < 4; t++)
      af[t] = *(const bf16x8_t*)&lA[(wm + t * 16 + lidx) * 32 + rsw];
#pragma unroll
    for (int t = 0; t < NT; t++)
      bf[t] = *(const bf16x8_t*)&lB[(wn + t * 16 + lidx) * 32 + rsw];
    if (c + 2 < NC) stage(c + 2, st);       // 2-chunk lead into the free slot
    __builtin_amdgcn_s_setprio(1);
#pragma unroll
    for (int mt = 0; mt < 4; mt++)
#pragma unroll
      for (int nt = 0; nt < NT; nt++)
        acc[mt][nt] = __builtin_amdgcn_mfma_f32_16x16x32_bf16(af[mt], bf[nt], acc[mt][nt], 0, 0, 0);
    __builtin_amdgcn_s_setprio(0);
    // chunk boundary: ensure chunk c+1 landed (own slice via vmcnt, others via barrier)
    if (c + 1 < NC) {
      if (c + 2 < NC) {
        if constexpr (LPC == 4) asm volatile("s_waitcnt vmcnt(4)" ::: "memory");
        else                    asm volatile("s_waitcnt vmcnt(3)" ::: "memory");
      } else {
        asm volatile("s_waitcnt vmcnt(0)" ::: "memory");
      }
      __builtin_amdgcn_s_barrier();
      __builtin_amdgcn_sched_barrier(0);
    }
    sl = (sl == 2) ? 0 : sl + 1;
    st = (st == 2) ? 0 : st + 1;
  }

  // ---------------- epilogues ----------------
  if (flags & 2) {
    // fused log-sum-exp partials: per wave, per row, reduce its 64-col strip
    const int pidx = blockIdx.y * 2 + (wave & 1);   // only used with TN=128, WN=64
#pragma unroll
    for (int mt = 0; mt < 4; mt++) {
#pragma unroll
      for (int r = 0; r < 4; r++) {
        const int row = m0 + wm + mt * 16 + quad * 4 + r;
        float vals[NT], m = -1e30f;
#pragma unroll
        for (int nt = 0; nt < NT; nt++) {
          const int colg = n0 + wn + nt * 16 + lidx;
          float v = acc[mt][nt][r] + bias[colg];
          if (colg >= 21128) v = -1e30f;           // mask pad cols
          vals[nt] = v;
          m = fmaxf(m, v);
        }
#pragma unroll
        for (int o = 1; o < 16; o <<= 1) m = fmaxf(m, __shfl_xor(m, o, 16));
        float s = 0.f;
#pragma unroll
        for (int nt = 0; nt < NT; nt++) s += __expf(vals[nt] - m);
#pragma unroll
        for (int o = 1; o < 16; o <<= 1) s += __shfl_xor(s, o, 16);
        if (lidx == 0) { float2 p; p.x = m; p.y = s; st2[(long)pidx * 8192 + row] = p; }
        const int t = yv[row];
        const int yc = (t == -100) ? 0 : t;
#pragma unroll
        for (int nt = 0; nt < NT; nt++)
          if (n0 + wn + nt * 16 + lidx == yc) tgt[row] = vals[nt];
      }
    }
    return;
  }

#pragma unroll
  for (int mt = 0; mt < 4; mt++) {
#pragma unroll
    for (int nt = 0; nt < NT; nt++) {
#pragma unroll
      for (int r = 0; r < 4; r++) {
        const int row = m0 + wm + mt * 16 + quad * 4 + r;
        const int col = n0 + wn + nt * 16 + lidx;
        float v = acc[mt][nt][r];
        if (bias) v += bias[col];
        if (flags & 1) v = 0.5f * v * (1.0f + erff(v * 0.70710678118f));
        const long o = (long)row * ldc + col;
        if (resid) v += resid[o];
        if (Cf) Cf[o] = v;
        if (Cb) Cb[o] = f2b(v);
      }
    }
  }
}

// ---------------- attention: per (qchunk, head, batch) block ----------------
__global__ __launch_bounds__(256, 2)
void attn_kernel(const unsigned short* __restrict__ qkv,   // [B*S][2304] = Q|K|V
                 unsigned short* __restrict__ ctx,         // [B*S][768]
                 const int* __restrict__ s1p)
{
  __shared__ unsigned short sh[32768];   // 64 KB: K [0,16384), V [16384,32768); P aliases K
  unsigned short* lK = sh;
  unsigned short* lV = sh + 16384;
  unsigned short* lP = sh;
  const int s1 = s1p[0];
  const int qc = blockIdx.x, h = blockIdx.y, b = blockIdx.z;
  const int tid = threadIdx.x;
  const int wave = tid >> 6, lane = tid & 63;
  const int quad = lane >> 4, lidx = lane & 15;
  const long tokbase = (long)b * 256 * 2304 + h * 64;

  {  // stage K,V with xor-swizzled 16B chunks (8 chunks per 64-wide row)
    const int kr = tid >> 3, c8 = tid & 7;
#pragma unroll
    for (int i = 0; i < 8; i++) {
      const int key = kr + i * 32;
      const unsigned short* src = qkv + tokbase + (long)key * 2304 + c8 * 8;
      const int sw = (c8 ^ (key & 7)) << 3;
      *(i32x4_t*)&lK[key * 64 + sw] = *(const i32x4_t*)(src + 768);
      *(i32x4_t*)&lV[key * 64 + sw] = *(const i32x4_t*)(src + 1536);
    }
  }
  bf16x8_t aq[2];
  {
    const int q = qc * 64 + wave * 16 + lidx;
    const unsigned short* qp = qkv + tokbase + (long)q * 2304;
    aq[0] = *(const bf16x8_t*)(qp + quad * 8);
    aq[1] = *(const bf16x8_t*)(qp + 32 + quad * 8);
  }
  __syncthreads();
  // QK^T: scores [16 q rows of this wave] x [256 keys]
  f32x4_t sc[16] = {};
#pragma unroll
  for (int kk = 0; kk < 2; kk++) {
#pragma unroll
    for (int nt = 0; nt < 16; nt++) {
      const int key = nt * 16 + lidx;
      const int ch = kk * 4 + quad;
      bf16x8_t bk = *(const bf16x8_t*)&lK[key * 64 + ((ch ^ (key & 7)) << 3)];
      sc[nt] = __builtin_amdgcn_mfma_f32_16x16x32_bf16(aq[kk], bk, sc[nt], 0, 0, 0);
    }
  }
  __syncthreads();   // all K reads done before P overwrites the same LDS
  const float scale = 0.125f;
  float rsum[4];
#pragma unroll
  for (int r = 0; r < 4; r++) {
    const int ql = wave * 16 + quad * 4 + r;
    const int q = qc * 64 + ql;
    float sv[16], m = -1e30f;
#pragma unroll
    for (int nt = 0; nt < 16; nt++) {
      const int key = nt * 16 + lidx;
      const float s = sc[nt][r] * scale + ((key < s1 || key <= q) ? 0.f : -1e9f);
      sv[nt] = s;
      m = fmaxf(m, s);
    }
#pragma unroll
    for (int o = 1; o < 16; o <<= 1) m = fmaxf(m, __shfl_xor(m, o, 16));
    float sum = 0.f;
#pragma unroll
    for (int nt = 0; nt < 16; nt++) {
      const float p = __expf(sv[nt] - m);
      sum += p;
      const int key = nt * 16 + lidx;
      lP[ql * 256 + ((((key >> 3) ^ (ql & 7))) << 3) + (key & 7)] = f2b(p);
    }
#pragma unroll
    for (int o = 1; o < 16; o <<= 1) sum += __shfl_xor(sum, o, 16);
    rsum[r] = sum;
  }
  __syncthreads();
  // PV: ctx[16 q][64 d] += P[16][256] x V[256][64]
  f32x4_t o4[4] = {};
#pragma unroll
  for (int kk = 0; kk < 8; kk++) {
    const int row = wave * 16 + lidx;
    const int ch = kk * 4 + quad;
    bf16x8_t ap = *(const bf16x8_t*)&lP[row * 256 + ((ch ^ (row & 7)) << 3)];
#pragma unroll
    for (int nt = 0; nt < 4; nt++) {
      bf16x8_t bv;
#pragma unroll
      for (int j = 0; j < 8; j++) {
        const int key = kk * 32 + quad * 8 + j;
        const int d = nt * 16 + lidx;
        bv[j] = (short)lV[key * 64 + (((d >> 3) ^ (key & 7)) << 3) + (d & 7)];
      }
      o4[nt] = __builtin_amdgcn_mfma_f32_16x16x32_bf16(ap, bv, o4[nt], 0, 0, 0);
    }
  }
#pragma unroll
  for (int nt = 0; nt < 4; nt++) {
#pragma unroll
    for (int r = 0; r < 4; r++) {
      const int q = qc * 64 + wave * 16 + quad * 4 + r;
      const int d = nt * 16 + lidx;
      ctx[(long)(b * 256 + q) * 768 + h * 64 + d] = f2b(o4[nt][r] / rsum[r]);
    }
  }
}

// ---------------- LayerNorm over H=768; writes f32 + bf16 ----------------
__global__ void ln_kernel(const float* __restrict__ in, const float* __restrict__ g,
                          const float* __restrict__ be, float* __restrict__ o32,
                          unsigned short* __restrict__ ob)
{
  __shared__ float sb1[4], sb2[4];
  const int row = blockIdx.x, tid = threadIdx.x;
  const float* x = in + (long)row * 768;
  float v[3], s = 0.f, ss = 0.f;
#pragma unroll
  for (int i = 0; i < 3; i++) { v[i] = x[tid + i * 256]; s += v[i]; ss += v[i] * v[i]; }
#pragma unroll
  for (int o = 32; o > 0; o >>= 1) { s += __shfl_down(s, o); ss += __shfl_down(ss, o); }
  if ((tid & 63) == 0) { sb1[tid >> 6] = s; sb2[tid >> 6] = ss; }
  __syncthreads();
  s = sb1[0] + sb1[1] + sb1[2] + sb1[3];
  ss = sb2[0] + sb2[1] + sb2[2] + sb2[3];
  const float mean = s * (1.f / 768.f);
  const float inv = rsqrtf(ss * (1.f / 768.f) - mean * mean + 1e-12f);
#pragma unroll
  for (int i = 0; i < 3; i++) {
    const int c = tid + i * 256;
    const float yv = (v[i] - mean) * inv * g[c] + be[c];
    if (o32) o32[(long)row * 768 + c] = yv;
    ob[(long)row * 768 + c] = f2b(yv);
  }
}

__global__ void embed_kernel(const int* __restrict__ xi, const float* __restrict__ we,
                             const float* __restrict__ pe, const float* __restrict__ te,
                             const float* __restrict__ g, const float* __restrict__ be,
                             float* __restrict__ o32, unsigned short* __restrict__ ob)
{
  __shared__ float sb1[4], sb2[4];
  const int row = blockIdx.x, tid = threadIdx.x;
  const int sidx = row & 255;
  const long id = xi[row];
  float v[3], s = 0.f, ss = 0.f;
#pragma unroll
  for (int i = 0; i < 3; i++) {
    const int c = tid + i * 256;
    v[i] = we[id * 768 + c] + pe[(long)sidx * 768 + c] + te[c];
    s += v[i]; ss += v[i] * v[i];
  }
#pragma unroll
  for (int o = 32; o > 0; o >>= 1) { s += __shfl_down(s, o); ss += __shfl_down(ss, o); }
  if ((tid & 63) == 0) { sb1[tid >> 6] = s; sb2[tid >> 6] = ss; }
  __syncthreads();
  s = sb1[0] + sb1[1] + sb1[2] + sb1[3];
  ss = sb2[0] + sb2[1] + sb2[2] + sb2[3];
  const float mean = s * (1.f / 768.f);
  const float inv = rsqrtf(ss * (1.f / 768.f) - mean * mean + 1e-12f);
#pragma unroll
  for (int i = 0; i < 3; i++) {
    const int c = tid + i * 256;
    const float yv = (v[i] - mean) * inv * g[c] + be[c];
    o32[(long)row * 768 + c] = yv;
    ob[(long)row * 768 + c] = f2b(yv);
  }
}

__global__ void zero2(float* p) { p[threadIdx.x] = 0.f; }

// merge the NPART per-column-strip (m,s) partials per row, then reduce the loss
__global__ void loss_final2(const float2* __restrict__ st2, const float* __restrict__ tgt,
                            const int* __restrict__ y, float* __restrict__ acc)
{
  __shared__ float sb1[4], sb2[4];
  const int tid = threadIdx.x;
  const int row = blockIdx.x * 256 + tid;
  float m = -1e30f, s = 0.f;
  for (int i = 0; i < NPART; i++) {
    const float2 p = st2[(long)i * 8192 + row];
    if (p.x > m) { s = s * __expf(m - p.x) + p.y; m = p.x; }
    else s += p.y * __expf(p.x - m);
  }
  const int t = y[row];
  float nll = 0.f, cv = 0.f;
  if (t != -100) {
    nll = m + __logf(s) - tgt[row];
    cv = 1.f;
  }
#pragma unroll
  for (int o = 32; o > 0; o >>= 1) { nll += __shfl_down(nll, o); cv += __shfl_down(cv, o); }
  if ((tid & 63) == 0) { sb1[tid >> 6] = nll; sb2[tid >> 6] = cv; }
  __syncthreads();
  if (tid == 0) {
    atomicAdd(&acc[0], sb1[0] + sb1[1] + sb1[2] + sb1[3]);
    atomicAdd(&acc[1], sb2[0] + sb2[1] + sb2[2] + sb2[3]);
  }
}
__global__ void loss_write(const float* __restrict__ acc, float* __restrict__ out)
{ out[0] = acc[0] / acc[1]; }

// ---------------- host launcher ----------------
extern "C" void kernel_launch(void* const* d_in, const int* in_sizes, int n_in,
                              void* d_out, int out_size, void* d_ws, size_t ws_size,
                              hipStream_t stream)
{
  const int* x = (const int*)d_in[0];
  const int* y = (const int*)d_in[1];
  const int* s1p = (const int*)d_in[2];
  const float* word = (const float*)d_in[4];
  const float* pos = (const float*)d_in[5];
  const float* typ = (const float*)d_in[6];
  const float* elg = (const float*)d_in[7];
  const float* elb = (const float*)d_in[8];
  const float* Wq = (const float*)d_in[9];
  const float* bq = (const float*)d_in[10];
  const float* Wk = (const float*)d_in[11];
  const float* bk = (const float*)d_in[12];
  const float* Wv = (const float*)d_in[13];
  const float* bvp = (const float*)d_in[14];
  const float* Wo = (const float*)d_in[15];
  const float* bo = (const float*)d_in[16];
  const float* l1g = (const float*)d_in[17];
  const float* l1b = (const float*)d_in[18];
  const float* W1 = (const float*)d_in[19];
  const float* b1 = (const float*)d_in[20];
  const float* W2 = (const float*)d_in[21];
  const float* b2 = (const float*)d_in[22];
  const float* l2g = (const float*)d_in[23];
  const float* l2b = (const float*)d_in[24];
  const float* cW = (const float*)d_in[25];
  const float* cb = (const float*)d_in[26];

  char* base = (char*)d_ws;
  size_t off = 0;
  auto alloc = [&](size_t bytes) -> void* {
    void* p = base + off;
    off = (off + bytes + 255) & ~(size_t)255;
    return p;
  };
  unsigned short* Wqkv = (unsigned short*)alloc(12ull * 2304 * 768 * 2);
  float* bqkv = (float*)alloc(12ull * 2304 * 4);
  unsigned short* Wot = (unsigned short*)alloc(12ull * 768 * 768 * 2);
  unsigned short* W1t = (unsigned short*)alloc(12ull * 3072 * 768 * 2);
  unsigned short* W2t = (unsigned short*)alloc(12ull * 768 * 3072 * 2);
  unsigned short* cWt = (unsigned short*)alloc(21248ull * 768 * 2);
  float* cbp = (float*)alloc(21248ull * 4);
  float* h32 = (float*)alloc(8192ull * 768 * 4);
  unsigned short* hb = (unsigned short*)alloc(8192ull * 768 * 2);
  unsigned short* qkvb = (unsigned short*)alloc(8192ull * 2304 * 2);
  unsigned short* ctxb = (unsigned short*)alloc(8192ull * 768 * 2);
  float* tmp32 = (float*)alloc(8192ull * 768 * 4);
  unsigned short* ffnb = (unsigned short*)alloc(8192ull * 3072 * 2);
  float2* st2 = (float2*)alloc((size_t)NPART * 8192 * 8);
  float* tgt = (float*)alloc(8192ull * 4);
  float* acc = (float*)alloc(256);

  const dim3 tt(32, 8);
  transpose_w<<<dim3(24, 24, 12), tt, 0, stream>>>(Wq, Wqkv, 768, 768, 768, 589824, 1769472);
  transpose_w<<<dim3(24, 24, 12), tt, 0, stream>>>(Wk, Wqkv + 589824, 768, 768, 768, 589824, 1769472);
  transpose_w<<<dim3(24, 24, 12), tt, 0, stream>>>(Wv, Wqkv + 1179648, 768, 768, 768, 589824, 1769472);
  transpose_w<<<dim3(24, 24, 12), tt, 0, stream>>>(Wo, Wot, 768, 768, 768, 589824, 589824);
  transpose_w<<<dim3(24, 96, 12), tt, 0, stream>>>(W1, W1t, 768, 3072, 3072, 2359296, 2359296);
  transpose_w<<<dim3(96, 24, 12), tt, 0, stream>>>(W2, W2t, 3072, 768, 768, 2359296, 2359296);
  transpose_w<<<dim3(24, 664, 1), tt, 0, stream>>>(cW, cWt, 768, 21128, 21248, 0, 0);
  build_bqkv<<<108, 256, 0, stream>>>(bq, bk, bvp, bqkv);
  build_clsb<<<83, 256, 0, stream>>>(cb, cbp);
  zero2<<<1, 2, 0, stream>>>(acc);

  embed_kernel<<<8192, 256, 0, stream>>>(x, word, pos, typ, elg, elb, h32, hb);

  for (int l = 0; l < 12; l++) {
    gemm_cnt<128, 128><<<dim3(64, 18), 256, 0, stream>>>(hb, Wqkv + (long)l * 1769472, bqkv + l * 2304,
                                                         nullptr, nullptr, qkvb, 768, 2304, 0,
                                                         nullptr, nullptr, nullptr);
    attn_kernel<<<dim3(4, 12, 32), 256, 0, stream>>>(qkvb, ctxb, s1p);
    gemm_cnt<64, 128><<<dim3(128, 6), 256, 0, stream>>>(ctxb, Wot + (long)l * 589824, bo + l * 768,
                                                        h32, tmp32, nullptr, 768, 768, 0,
                                                        nullptr, nullptr, nullptr);
    ln_kernel<<<8192, 256, 0, stream>>>(tmp32, l1g + l * 768, l1b + l * 768, h32, hb);
    gemm_cnt<128, 128><<<dim3(64, 24), 256, 0, stream>>>(hb, W1t + (long)l * 2359296, b1 + l * 3072,
                                                         nullptr, nullptr, ffnb, 768, 3072, 1,
                                                         nullptr, nullptr, nullptr);
    gemm_cnt<64, 128><<<dim3(128, 6), 256, 0, stream>>>(ffnb, W2t + (long)l * 2359296, b2 + l * 768,
                                                        h32, tmp32, nullptr, 3072, 768, 0,
                                                        nullptr, nullptr, nullptr);
    ln_kernel<<<8192, 256, 0, stream>>>(tmp32, l2g + l * 768, l2b + l * 768, h32, hb);
  }

  // classifier + fused LSE: one dispatch over all 21248 (padded) columns
  gemm_cnt<128, 128><<<dim3(64, 166), 256, 0, stream>>>(hb, cWt, cbp,
                                                        nullptr, nullptr, nullptr,
                                                        768, 0, 2, y, st2, tgt);
  loss_final2<<<32, 256, 0, stream>>>(st2, tgt, y, acc);
  loss_write<<<1, 1, 0, stream>>>(acc, (float*)d_out);
}